// Round 1
// baseline (687.363 us; speedup 1.0000x reference)
//
#include <hip/hip_runtime.h>
#include <cfloat>
#include <cmath>

#define NHEADS 3
#define HIDC   64
#define HCC    192   // NHEADS*HIDC
#define EMBC   128

// ---- monotone float<->uint mapping for atomicMax on floats (init = 0) ----
__device__ __forceinline__ unsigned fmap(float f) {
  unsigned u = __float_as_uint(f);
  return (u & 0x80000000u) ? ~u : (u | 0x80000000u);
}
__device__ __forceinline__ float funmap(unsigned m) {
  return __uint_as_float((m & 0x80000000u) ? (m ^ 0x80000000u) : ~m);
}

// ---- xl = pe@Wl^T + bl ; xr = pe@Wr^T + br  (fp32 vector GEMM, K=128) ----
__global__ __launch_bounds__(256) void gemm_kernel(
    const float* __restrict__ pe,
    const float* __restrict__ Wl, const float* __restrict__ bl,
    const float* __restrict__ Wr, const float* __restrict__ br,
    float* __restrict__ xl, float* __restrict__ xr, int N)
{
  __shared__ float As[64][132];   // +4 pad: i-groups land on distinct banks
  const int t = threadIdx.x;
  const int n0 = blockIdx.x * 64;

  for (int f = t; f < 64 * 32; f += 256) {   // 2048 float4 loads
    int row = f >> 5;
    int c4  = (f & 31) << 2;
    int n = n0 + row;
    float4 v = make_float4(0.f, 0.f, 0.f, 0.f);
    if (n < N) v = *(const float4*)(pe + (size_t)n * EMBC + c4);
    As[row][c4]   = v.x; As[row][c4+1] = v.y;
    As[row][c4+2] = v.z; As[row][c4+3] = v.w;
  }
  __syncthreads();

  const int ig = t >> 4;   // node group 0..15 (4 nodes each)
  const int jg = t & 15;   // col  group 0..15 (12 cols each)

  for (int mat = 0; mat < 2; ++mat) {
    const float* __restrict__ W    = mat ? Wr : Wl;
    const float* __restrict__ bias = mat ? br : bl;
    float*       __restrict__ xo   = mat ? xr : xl;

    float acc[4][12];
    #pragma unroll
    for (int a = 0; a < 4; ++a)
      #pragma unroll
      for (int c = 0; c < 12; ++c) acc[a][c] = 0.f;

    for (int k = 0; k < EMBC; k += 4) {
      float4 av[4];
      #pragma unroll
      for (int a = 0; a < 4; ++a) av[a] = *(const float4*)&As[ig*4 + a][k];
      #pragma unroll
      for (int c = 0; c < 12; ++c) {
        float4 w = *(const float4*)(W + (size_t)(jg*12 + c) * EMBC + k);
        #pragma unroll
        for (int a = 0; a < 4; ++a)
          acc[a][c] += av[a].x*w.x + av[a].y*w.y + av[a].z*w.z + av[a].w*w.w;
      }
    }
    #pragma unroll
    for (int a = 0; a < 4; ++a) {
      int n = n0 + ig*4 + a;
      if (n < N) {
        #pragma unroll
        for (int c = 0; c < 12; ++c)
          xo[(size_t)n * HCC + jg*12 + c] = acc[a][c] + bias[jg*12 + c];
      }
    }
  }
}

// ---- pj[n,h] = xl[n,h,:] . Wout   (one wave per node) ----
__global__ __launch_bounds__(256) void pj_kernel(
    const float* __restrict__ xl, const float* __restrict__ Wout,
    float* __restrict__ pj, int N)
{
  int gid  = (blockIdx.x * 256 + threadIdx.x) >> 6;
  int lane = threadIdx.x & 63;
  if (gid >= N) return;
  float wv = Wout[lane];
  const float* row = xl + (size_t)gid * HCC;
  float s0 = row[lane]       * wv;
  float s1 = row[64 + lane]  * wv;
  float s2 = row[128 + lane] * wv;
  #pragma unroll
  for (int off = 32; off; off >>= 1) {
    s0 += __shfl_xor(s0, off);
    s1 += __shfl_xor(s1, off);
    s2 += __shfl_xor(s2, off);
  }
  if (lane < 3) pj[gid*3 + lane] = (lane == 0) ? s0 : (lane == 1 ? s1 : s2);
}

// ---- single edge pass: a -> exp(a) -> atomic {asum, numer} per (dst,h) ----
__global__ __launch_bounds__(256) void edge_kernel(
    const int* __restrict__ ei, const float* __restrict__ ea,
    const float* __restrict__ xl, const float* __restrict__ xr,
    const float* __restrict__ pj, const float* __restrict__ We,
    const float* __restrict__ att,
    float* __restrict__ asum, float* __restrict__ numer, int E)
{
  int e    = (blockIdx.x * 256 + threadIdx.x) >> 6;   // one wave per edge
  int lane = threadIdx.x & 63;
  if (e >= E) return;
  int src = ei[e];
  int dst = ei[E + e];
  float eav = ea[e];
  const float* xls = xl + (size_t)src * HCC;
  const float* xrd = xr + (size_t)dst * HCC;

  float m0 = xls[lane]       + xrd[lane]       + eav * We[lane];
  float m1 = xls[64 + lane]  + xrd[64 + lane]  + eav * We[64 + lane];
  float m2 = xls[128 + lane] + xrd[128 + lane] + eav * We[128 + lane];
  float s0 = (m0 > 0.f ? m0 : 0.2f * m0) * att[lane];
  float s1 = (m1 > 0.f ? m1 : 0.2f * m1) * att[64 + lane];
  float s2 = (m2 > 0.f ? m2 : 0.2f * m2) * att[128 + lane];

  #pragma unroll
  for (int off = 32; off; off >>= 1) {
    s0 += __shfl_xor(s0, off);
    s1 += __shfl_xor(s1, off);
    s2 += __shfl_xor(s2, off);
  }
  if (lane < 3) {
    float a  = (lane == 0) ? s0 : (lane == 1 ? s1 : s2);
    float ex = expf(a);   // |a| small by construction: max-free softmax is safe
    atomicAdd(asum  + dst*3 + lane, ex);
    atomicAdd(numer + dst*3 + lane, ex * pj[src*3 + lane]);
  }
}

// ---- scores[n] = (1/3) sum_h numer/asum ; block-reduce max ----
__global__ __launch_bounds__(256) void score_kernel(
    const float* __restrict__ numer, const float* __restrict__ asum,
    float* __restrict__ scores, unsigned* __restrict__ smax, int N)
{
  int n = blockIdx.x * 256 + threadIdx.x;
  int t = threadIdx.x;
  float s = -FLT_MAX;
  if (n < N) {
    float acc = 0.f;
    #pragma unroll
    for (int h = 0; h < 3; ++h) {
      float d = asum[n*3 + h];
      if (d > 0.f) acc += numer[n*3 + h] / d;   // empty segment -> 0 (matches ref)
    }
    s = acc / 3.f;
    scores[n] = s;
  }
  __shared__ float red[256];
  red[t] = s;
  __syncthreads();
  for (int w = 128; w; w >>= 1) {
    if (t < w) red[t] = fmaxf(red[t], red[t + w]);
    __syncthreads();
  }
  if (t == 0) atomicMax(smax, fmap(red[0]));
}

__global__ __launch_bounds__(256) void expsum_kernel(
    const float* __restrict__ scores, const unsigned* __restrict__ smax,
    float* __restrict__ sumexp, float* __restrict__ out, int N)
{
  int n = blockIdx.x * 256 + threadIdx.x;
  int t = threadIdx.x;
  float m = funmap(*smax);
  float e = 0.f;
  if (n < N) {
    e = expf(scores[n] - m);
    out[n] = e;
  }
  __shared__ float red[256];
  red[t] = e;
  __syncthreads();
  for (int w = 128; w; w >>= 1) {
    if (t < w) red[t] += red[t + w];
    __syncthreads();
  }
  if (t == 0) atomicAdd(sumexp, red[0]);
}

__global__ __launch_bounds__(256) void norm_kernel(
    float* __restrict__ out, const float* __restrict__ sumexp, int N)
{
  int n = blockIdx.x * 256 + threadIdx.x;
  if (n < N) out[n] /= *sumexp;
}

extern "C" void kernel_launch(void* const* d_in, const int* in_sizes, int n_in,
                              void* d_out, int out_size, void* d_ws, size_t ws_size,
                              hipStream_t stream) {
  const int*   ei   = (const int*)  d_in[0];
  const float* ea   = (const float*)d_in[1];
  const float* pe   = (const float*)d_in[2];
  // d_in[3] sim_w: softmax over 1 element == 1.0 -> unused
  const float* Wl   = (const float*)d_in[4];
  const float* bl   = (const float*)d_in[5];
  const float* Wr   = (const float*)d_in[6];
  const float* br   = (const float*)d_in[7];
  const float* We   = (const float*)d_in[8];
  const float* att  = (const float*)d_in[9];
  // d_in[10] bias_gnn, d_in[12] bout: constant shift of scores -> softmax-invariant, unused
  const float* Wout = (const float*)d_in[11];

  const int E = in_sizes[0] / 2;
  const int N = in_sizes[2] / EMBC;
  float* out = (float*)d_out;

  // workspace layout (floats)
  float* ws     = (float*)d_ws;
  float* asum   = ws;                        // 3N
  float* numer  = ws + (size_t)3 * N;        // 3N
  unsigned* smax = (unsigned*)(ws + (size_t)6 * N);  // 1 (mapped, init 0 == -inf)
  float* sumexp = ws + (size_t)6 * N + 1;    // 1
  float* xl     = ws + (size_t)6 * N + 16;   // N*192
  float* xr     = xl + (size_t)N * HCC;      // N*192
  float* pj     = xr + (size_t)N * HCC;      // 3N
  float* scores = pj + (size_t)3 * N;        // N

  // zero the accumulators (ws is poisoned 0xAA before every call)
  hipMemsetAsync(ws, 0, ((size_t)6 * N + 2) * sizeof(float), stream);

  gemm_kernel  <<<(N + 63) / 64,   256, 0, stream>>>(pe, Wl, bl, Wr, br, xl, xr, N);
  pj_kernel    <<<(N + 3) / 4,     256, 0, stream>>>(xl, Wout, pj, N);
  edge_kernel  <<<(E + 3) / 4,     256, 0, stream>>>(ei, ea, xl, xr, pj, We, att, asum, numer, E);
  score_kernel <<<(N + 255) / 256, 256, 0, stream>>>(numer, asum, scores, smax, N);
  expsum_kernel<<<(N + 255) / 256, 256, 0, stream>>>(scores, smax, sumexp, out, N);
  norm_kernel  <<<(N + 255) / 256, 256, 0, stream>>>(out, sumexp, N);
}

// Round 2
// 434.880 us; speedup vs baseline: 1.5806x; 1.5806x over previous
//
#include <hip/hip_runtime.h>
#include <cfloat>
#include <cmath>

#define NHEADS 3
#define HIDC   64
#define HCC    192   // NHEADS*HIDC
#define EMBC   128

// ---- monotone float<->uint mapping for atomicMax on floats (init = 0) ----
__device__ __forceinline__ unsigned fmap(float f) {
  unsigned u = __float_as_uint(f);
  return (u & 0x80000000u) ? ~u : (u | 0x80000000u);
}
__device__ __forceinline__ float funmap(unsigned m) {
  return __uint_as_float((m & 0x80000000u) ? (m ^ 0x80000000u) : ~m);
}

__device__ __forceinline__ void fma4(float4& acc, float s, const float4& w) {
  acc.x = fmaf(s, w.x, acc.x);
  acc.y = fmaf(s, w.y, acc.y);
  acc.z = fmaf(s, w.z, acc.z);
  acc.w = fmaf(s, w.w, acc.w);
}

// ---- fused xl|xr = pe @ [Wl;Wr]^T + [bl;br]  (fp32, LDS-staged, reg-tiled) ----
// Tile: 64 nodes x 384 cols. Thread (ig,jg) = (t>>4, t&15) computes
// nodes ig*4..+3, cols {c6*64 + jg*4 ..+3 : c6 in 0..5}. acc = float4[4][6].
__global__ __launch_bounds__(256) void gemm_kernel(
    const float* __restrict__ pe,
    const float* __restrict__ Wl, const float* __restrict__ bl,
    const float* __restrict__ Wr, const float* __restrict__ br,
    float* __restrict__ xl, float* __restrict__ xr, int N)
{
  __shared__ float As[64][132];   // node-major, pad 4: wave reads 2-way alias (free)
  __shared__ float Ws[16][388];   // k-major tile,  col reads contiguous per wave
  const int t  = threadIdx.x;
  const int n0 = blockIdx.x * 64;
  const int ig = t >> 4;
  const int jg = t & 15;

  // stage pe tile (once)
  for (int f = t; f < 64 * 32; f += 256) {
    int row = f >> 5;
    int c4  = (f & 31) << 2;
    int n = n0 + row;
    float4 v = make_float4(0.f, 0.f, 0.f, 0.f);
    if (n < N) v = *(const float4*)(pe + (size_t)n * EMBC + c4);
    As[row][c4]   = v.x; As[row][c4+1] = v.y;
    As[row][c4+2] = v.z; As[row][c4+3] = v.w;
  }

  float4 acc[4][6];
  #pragma unroll
  for (int a = 0; a < 4; ++a)
    #pragma unroll
    for (int c = 0; c < 6; ++c) acc[a][c] = make_float4(0.f, 0.f, 0.f, 0.f);

  for (int kt = 0; kt < EMBC; kt += 16) {
    __syncthreads();   // protects As on first iter, Ws reuse on later iters
    // stage W k-tile: Ws[kk][c] = W[c][kt+kk]  (transpose via LDS)
    for (int f = t; f < 1536; f += 256) {
      int c  = f >> 2;
      int kq = f & 3;
      const float* wp = (c < HCC ? Wl + (size_t)c * EMBC
                                 : Wr + (size_t)(c - HCC) * EMBC) + kt + kq * 4;
      float4 v = *(const float4*)wp;
      Ws[kq*4+0][c] = v.x; Ws[kq*4+1][c] = v.y;
      Ws[kq*4+2][c] = v.z; Ws[kq*4+3][c] = v.w;
    }
    __syncthreads();

    #pragma unroll
    for (int k4 = 0; k4 < 16; k4 += 4) {
      float4 av[4];
      #pragma unroll
      for (int a = 0; a < 4; ++a)
        av[a] = *(const float4*)&As[ig*4 + a][kt + k4];
      #pragma unroll
      for (int kk = 0; kk < 4; ++kk) {
        #pragma unroll
        for (int c6 = 0; c6 < 6; ++c6) {
          float4 w = *(const float4*)&Ws[k4 + kk][c6*64 + jg*4];
          #pragma unroll
          for (int a = 0; a < 4; ++a)
            fma4(acc[a][c6], ((const float*)&av[a])[kk], w);
        }
      }
    }
  }

  // epilogue: + bias, split cols into xl / xr
  #pragma unroll
  for (int c6 = 0; c6 < 6; ++c6) {
    int col = c6*64 + jg*4;
    const float* bp = (col < HCC) ? (bl + col) : (br + col - HCC);
    float4 b = *(const float4*)bp;
    float* xo = (col < HCC) ? xl : xr;
    int colo = (col < HCC) ? col : col - HCC;
    #pragma unroll
    for (int a = 0; a < 4; ++a) {
      int n = n0 + ig*4 + a;
      if (n < N) {
        float4 r = acc[a][c6];
        r.x += b.x; r.y += b.y; r.z += b.z; r.w += b.w;
        *(float4*)(xo + (size_t)n * HCC + colo) = r;
      }
    }
  }
}

// ---- pj[n,h] = xl[n,h,:] . Wout   (one wave per node) ----
__global__ __launch_bounds__(256) void pj_kernel(
    const float* __restrict__ xl, const float* __restrict__ Wout,
    float* __restrict__ pj, int N)
{
  int gid  = (blockIdx.x * 256 + threadIdx.x) >> 6;
  int lane = threadIdx.x & 63;
  if (gid >= N) return;
  float wv = Wout[lane];
  const float* row = xl + (size_t)gid * HCC;
  float s0 = row[lane]       * wv;
  float s1 = row[64 + lane]  * wv;
  float s2 = row[128 + lane] * wv;
  #pragma unroll
  for (int off = 32; off; off >>= 1) {
    s0 += __shfl_xor(s0, off);
    s1 += __shfl_xor(s1, off);
    s2 += __shfl_xor(s2, off);
  }
  if (lane < 3) pj[gid*3 + lane] = (lane == 0) ? s0 : (lane == 1 ? s1 : s2);
}

// ---- single edge pass: 48 active lanes, float4 per lane, 16-lane head groups ----
__global__ __launch_bounds__(256) void edge_kernel(
    const int* __restrict__ ei, const float* __restrict__ ea,
    const float* __restrict__ xl, const float* __restrict__ xr,
    const float* __restrict__ pj, const float* __restrict__ We,
    const float* __restrict__ att,
    float* __restrict__ asum, float* __restrict__ numer, int E)
{
  int e    = (blockIdx.x * 256 + threadIdx.x) >> 6;   // one wave per edge
  int lane = threadIdx.x & 63;
  if (e >= E) return;
  int src = ei[e];
  int dst = ei[E + e];
  float eav = ea[e];

  float s = 0.f;
  if (lane < 48) {
    const float4 xls = *(const float4*)(xl + (size_t)src * HCC + lane*4);
    const float4 xrd = *(const float4*)(xr + (size_t)dst * HCC + lane*4);
    const float4 wev = *(const float4*)(We + lane*4);
    const float4 atv = *(const float4*)(att + lane*4);
    float m0 = xls.x + xrd.x + eav * wev.x;
    float m1 = xls.y + xrd.y + eav * wev.y;
    float m2 = xls.z + xrd.z + eav * wev.z;
    float m3 = xls.w + xrd.w + eav * wev.w;
    s = (m0 > 0.f ? m0 : 0.2f*m0) * atv.x
      + (m1 > 0.f ? m1 : 0.2f*m1) * atv.y
      + (m2 > 0.f ? m2 : 0.2f*m2) * atv.z
      + (m3 > 0.f ? m3 : 0.2f*m3) * atv.w;
  }
  // reduce within 16-lane groups (one head per group; xor<=8 stays in-group)
  s += __shfl_xor(s, 8);
  s += __shfl_xor(s, 4);
  s += __shfl_xor(s, 2);
  s += __shfl_xor(s, 1);
  if (lane < 48 && (lane & 15) == 0) {
    int h = lane >> 4;
    float ex = expf(s);   // |a| small by construction: max-free softmax is safe
    atomicAdd(asum  + dst*3 + h, ex);
    atomicAdd(numer + dst*3 + h, ex * pj[src*3 + h]);
  }
}

// ---- scores[n] = (1/3) sum_h numer/asum ; block-reduce max ----
__global__ __launch_bounds__(256) void score_kernel(
    const float* __restrict__ numer, const float* __restrict__ asum,
    float* __restrict__ scores, unsigned* __restrict__ smax, int N)
{
  int n = blockIdx.x * 256 + threadIdx.x;
  int t = threadIdx.x;
  float s = -FLT_MAX;
  if (n < N) {
    float acc = 0.f;
    #pragma unroll
    for (int h = 0; h < 3; ++h) {
      float d = asum[n*3 + h];
      if (d > 0.f) acc += numer[n*3 + h] / d;   // empty segment -> 0 (matches ref)
    }
    s = acc / 3.f;
    scores[n] = s;
  }
  __shared__ float red[256];
  red[t] = s;
  __syncthreads();
  for (int w = 128; w; w >>= 1) {
    if (t < w) red[t] = fmaxf(red[t], red[t + w]);
    __syncthreads();
  }
  if (t == 0) atomicMax(smax, fmap(red[0]));
}

__global__ __launch_bounds__(256) void expsum_kernel(
    const float* __restrict__ scores, const unsigned* __restrict__ smax,
    float* __restrict__ sumexp, float* __restrict__ out, int N)
{
  int n = blockIdx.x * 256 + threadIdx.x;
  int t = threadIdx.x;
  float m = funmap(*smax);
  float e = 0.f;
  if (n < N) {
    e = expf(scores[n] - m);
    out[n] = e;
  }
  __shared__ float red[256];
  red[t] = e;
  __syncthreads();
  for (int w = 128; w; w >>= 1) {
    if (t < w) red[t] += red[t + w];
    __syncthreads();
  }
  if (t == 0) atomicAdd(sumexp, red[0]);
}

__global__ __launch_bounds__(256) void norm_kernel(
    float* __restrict__ out, const float* __restrict__ sumexp, int N)
{
  int n = blockIdx.x * 256 + threadIdx.x;
  if (n < N) out[n] /= *sumexp;
}

extern "C" void kernel_launch(void* const* d_in, const int* in_sizes, int n_in,
                              void* d_out, int out_size, void* d_ws, size_t ws_size,
                              hipStream_t stream) {
  const int*   ei   = (const int*)  d_in[0];
  const float* ea   = (const float*)d_in[1];
  const float* pe   = (const float*)d_in[2];
  // d_in[3] sim_w: softmax over 1 element == 1.0 -> unused
  const float* Wl   = (const float*)d_in[4];
  const float* bl   = (const float*)d_in[5];
  const float* Wr   = (const float*)d_in[6];
  const float* br   = (const float*)d_in[7];
  const float* We   = (const float*)d_in[8];
  const float* att  = (const float*)d_in[9];
  // d_in[10] bias_gnn, d_in[12] bout: constant shift of scores -> softmax-invariant, unused
  const float* Wout = (const float*)d_in[11];

  const int E = in_sizes[0] / 2;
  const int N = in_sizes[2] / EMBC;
  float* out = (float*)d_out;

  // workspace layout (floats)
  float* ws     = (float*)d_ws;
  float* asum   = ws;                        // 3N
  float* numer  = ws + (size_t)3 * N;        // 3N
  unsigned* smax = (unsigned*)(ws + (size_t)6 * N);  // 1 (mapped, init 0 == -inf)
  float* sumexp = ws + (size_t)6 * N + 1;    // 1
  float* xl     = ws + (size_t)6 * N + 16;   // N*192
  float* xr     = xl + (size_t)N * HCC;      // N*192
  float* pj     = xr + (size_t)N * HCC;      // 3N
  float* scores = pj + (size_t)3 * N;        // N

  // zero the accumulators (ws is poisoned 0xAA before every call)
  hipMemsetAsync(ws, 0, ((size_t)6 * N + 2) * sizeof(float), stream);

  gemm_kernel  <<<(N + 63) / 64,   256, 0, stream>>>(pe, Wl, bl, Wr, br, xl, xr, N);
  pj_kernel    <<<(N + 3) / 4,     256, 0, stream>>>(xl, Wout, pj, N);
  edge_kernel  <<<(E + 3) / 4,     256, 0, stream>>>(ei, ea, xl, xr, pj, We, att, asum, numer, E);
  score_kernel <<<(N + 255) / 256, 256, 0, stream>>>(numer, asum, scores, smax, N);
  expsum_kernel<<<(N + 255) / 256, 256, 0, stream>>>(scores, smax, sumexp, out, N);
  norm_kernel  <<<(N + 255) / 256, 256, 0, stream>>>(out, sumexp, N);
}